// Round 5
// baseline (159.914 us; speedup 1.0000x reference)
//
#include <hip/hip_runtime.h>
#include <cmath>

// SSIM fused kernel for B=16, C=3, H=W=512 fp32 images.
// R5: V-first separable conv (R4) + LDS-read halving.
// R4 post-mortem: VALU cut worked (VALUBusy 72->35%) but time rose ->
// LDS pipe was the real roof (11x ds_read_b128/row/thread ~= 46us/CU busy).
// Changes:
//  - V-filtered quantities stored as TWO float2 arrays (AB, SP) instead of
//    one float4: a thread doing 2 adjacent cols reads slots 2u..2u+11 as
//    6 aligned b128 per array = 12 reads/2cols vs 22 (-45% LDS).
//  - TWO output rows per iteration: waves 0-3 H-conv row r, waves 4-7 row
//    r+1 (wave-uniform sel) -> all waves busy, barriers halve (16/block).
//  - Each (A,B)/(S,P) quad half is an even-aligned VGPR pair -> pk-fma
//    count unchanged. Writes are contiguous b64 (conflict-free; R1's
//    conflicts came from STRIDED b64 writes, avoided here).
// Sentinels: WRITE_SIZE ~24KB (no spill), conflicts ~0.

#define IMG_H 512
#define IMG_W 512
#define STRIPE 32
#define NSTR (IMG_H / STRIPE)      // 16
#define NPLANES 48                 // 16*3
#define NBLOCKS (NPLANES * NSTR)   // 768
#define SSIM_C1 (0.01f * 0.01f)
#define SSIM_C2 (0.03f * 0.03f)

typedef float f32x2 __attribute__((ext_vector_type(2)));

struct W2x11 { float2 w[11]; };   // pre-broadcast {w,w} pairs

__launch_bounds__(512, 2)
__global__ void ssim_main(const float* __restrict__ img1,
                          const float* __restrict__ img2,
                          float* __restrict__ blockSums, W2x11 wv) {
    // slot s holds V-filtered col (x0-5+s); [dbuf][row-of-pair][slot]
    __shared__ __align__(16) float2 abL[2][2][532];
    __shared__ __align__(16) float2 spL[2][2][532];
    __shared__ float red[8];

    const int x = threadIdx.x;            // 0..511, one column for V-phase
    const int bid = blockIdx.x;
    const int plane = bid >> 4;           // /NSTR
    const int stripe = bid & (NSTR - 1);
    const int y0 = stripe * STRIPE;
    const size_t base = (size_t)plane * (IMG_H * IMG_W);

    // zero halo pads (slots 0..4 and 517..521; all dbuf x row arrays)
    if (x < 10) {
        const int col = (x < 5) ? x : (x + 512);
#pragma unroll
        for (int d = 0; d < 2; ++d)
#pragma unroll
            for (int r = 0; r < 2; ++r) {
                abL[d][r][col] = make_float2(0.f, 0.f);
                spL[d][r][col] = make_float2(0.f, 0.f);
            }
    }

    // vertical ring of RAW packed pairs, static-indexed via unroll
    f32x2 rAB[11], rSP[11];
    float acc = 0.f;

    // preload staged rows 0,1 (image rows y0-5, y0-4)
    float pa0 = 0.f, pb0 = 0.f, pa1 = 0.f, pb1 = 0.f;
    {
        const int r0 = y0 - 5, r1 = y0 - 4;
        if (r0 >= 0) {
            pa0 = img1[base + (size_t)r0 * IMG_W + x];
            pb0 = img2[base + (size_t)r0 * IMG_W + x];
        }
        if (r1 >= 0) {
            pa1 = img1[base + (size_t)r1 * IMG_W + x];
            pb1 = img2[base + (size_t)r1 * IMG_W + x];
        }
    }

    int buf = 0;
#pragma unroll 1
    for (int c = 0; c < 2; ++c) {
#pragma unroll
        for (int jp = 0; jp < 11; ++jp) {
            const int p = c * 11 + jp;     // pair index 0..21; rows 2p,2p+1
            if (p < 21) {                  // block-uniform guard
                const int j1 = (2 * jp) % 11;      // ring slot of row 2p
                const int j2 = (2 * jp + 1) % 11;  // ring slot of row 2p+1
                // push raw row 2p (sq/pr computed once per pixel)
                {
                    f32x2 ab; ab.x = pa0; ab.y = pb0;
                    f32x2 sp;
                    sp.x = fmaf(pb0, pb0, pa0 * pa0);
                    sp.y = pa0 * pb0;
                    rAB[j1] = ab; rSP[j1] = sp;
                }
                if (p >= 5) {  // V-conv for staged row 2p (ring full)
                    f32x2 vAB = {0.f, 0.f}, vSP = {0.f, 0.f};
#pragma unroll
                    for (int k = 0; k < 11; ++k) {
                        const int s = (2 * jp + 1 + k) % 11;   // static
                        f32x2 w2; w2.x = wv.w[k].x; w2.y = wv.w[k].y;
                        vAB = __builtin_elementwise_fma(w2, rAB[s], vAB);
                        vSP = __builtin_elementwise_fma(w2, rSP[s], vSP);
                    }
                    abL[buf][0][x + 5] = make_float2(vAB.x, vAB.y);
                    spL[buf][0][x + 5] = make_float2(vSP.x, vSP.y);
                }
                // push raw row 2p+1
                {
                    f32x2 ab; ab.x = pa1; ab.y = pb1;
                    f32x2 sp;
                    sp.x = fmaf(pb1, pb1, pa1 * pa1);
                    sp.y = pa1 * pb1;
                    rAB[j2] = ab; rSP[j2] = sp;
                }
                if (p >= 5) {  // V-conv for staged row 2p+1
                    f32x2 vAB = {0.f, 0.f}, vSP = {0.f, 0.f};
#pragma unroll
                    for (int k = 0; k < 11; ++k) {
                        const int s = (2 * jp + 2 + k) % 11;   // static
                        f32x2 w2; w2.x = wv.w[k].x; w2.y = wv.w[k].y;
                        vAB = __builtin_elementwise_fma(w2, rAB[s], vAB);
                        vSP = __builtin_elementwise_fma(w2, rSP[s], vSP);
                    }
                    abL[buf][1][x + 5] = make_float2(vAB.x, vAB.y);
                    spL[buf][1][x + 5] = make_float2(vSP.x, vSP.y);
                }
                // prefetch staged rows 2p+2, 2p+3 (consumed next iter)
                pa0 = 0.f; pb0 = 0.f; pa1 = 0.f; pb1 = 0.f;
                if (p + 1 < 21) {
                    const int rn0 = y0 - 5 + 2 * p + 2;
                    const int rn1 = rn0 + 1;
                    if (rn0 >= 0 && rn0 < IMG_H) {
                        pa0 = img1[base + (size_t)rn0 * IMG_W + x];
                        pb0 = img2[base + (size_t)rn0 * IMG_W + x];
                    }
                    if (rn1 >= 0 && rn1 < IMG_H) {
                        pa1 = img1[base + (size_t)rn1 * IMG_W + x];
                        pb1 = img2[base + (size_t)rn1 * IMG_W + x];
                    }
                }
                if (p >= 5) {
                    __syncthreads();
                    // H-phase: waves 0-3 -> row 2p, waves 4-7 -> row 2p+1;
                    // each thread does cols 2u, 2u+1.
                    const int sel = x >> 8;        // wave-uniform
                    const int u = x & 255;
                    const float2* Ap = abL[buf][sel];
                    const float2* Sp = spL[buf][sel];
                    f32x2 hAB0 = {0.f, 0.f}, hAB1 = {0.f, 0.f};
                    f32x2 hSP0 = {0.f, 0.f}, hSP1 = {0.f, 0.f};
#pragma unroll
                    for (int m = 0; m < 6; ++m) {  // 6 b128 per array
                        const float4 q = *(const float4*)(&Ap[2 * u + 2 * m]);
                        f32x2 lo; lo.x = q.x; lo.y = q.y;   // slot 2u+2m
                        f32x2 hi; hi.x = q.z; hi.y = q.w;   // slot 2u+2m+1
                        f32x2 w2;
                        // col 2u: slot 2m -> tap 2m; slot 2m+1 -> tap 2m+1
                        w2.x = wv.w[2 * m].x; w2.y = wv.w[2 * m].y;
                        hAB0 = __builtin_elementwise_fma(w2, lo, hAB0);
                        hAB1 = __builtin_elementwise_fma(w2, hi, hAB1); // col 2u+1 tap 2m
                        if (2 * m + 1 <= 10) {
                            w2.x = wv.w[2 * m + 1].x; w2.y = wv.w[2 * m + 1].y;
                            hAB0 = __builtin_elementwise_fma(w2, hi, hAB0);
                        }
                        if (2 * m - 1 >= 0) {      // col 2u+1: slot 2m -> tap 2m-1
                            w2.x = wv.w[2 * m - 1].x; w2.y = wv.w[2 * m - 1].y;
                            hAB1 = __builtin_elementwise_fma(w2, lo, hAB1);
                        }
                    }
#pragma unroll
                    for (int m = 0; m < 6; ++m) {
                        const float4 q = *(const float4*)(&Sp[2 * u + 2 * m]);
                        f32x2 lo; lo.x = q.x; lo.y = q.y;
                        f32x2 hi; hi.x = q.z; hi.y = q.w;
                        f32x2 w2;
                        w2.x = wv.w[2 * m].x; w2.y = wv.w[2 * m].y;
                        hSP0 = __builtin_elementwise_fma(w2, lo, hSP0);
                        hSP1 = __builtin_elementwise_fma(w2, hi, hSP1);
                        if (2 * m + 1 <= 10) {
                            w2.x = wv.w[2 * m + 1].x; w2.y = wv.w[2 * m + 1].y;
                            hSP0 = __builtin_elementwise_fma(w2, hi, hSP0);
                        }
                        if (2 * m - 1 >= 0) {
                            w2.x = wv.w[2 * m - 1].x; w2.y = wv.w[2 * m - 1].y;
                            hSP1 = __builtin_elementwise_fma(w2, lo, hSP1);
                        }
                    }
                    // epilogue for col 2u
                    {
                        const float vA = hAB0.x, vB = hAB0.y;
                        const float vS = hSP0.x, vP = hSP0.y;
                        const float mu11 = vA * vA, mu22 = vB * vB;
                        const float mu12 = vA * vB;
                        const float num = fmaf(2.f, mu12, SSIM_C1) *
                                          fmaf(2.f, vP - mu12, SSIM_C2);
                        const float d1  = mu11 + mu22;
                        const float den = (d1 + SSIM_C1) * ((vS - d1) + SSIM_C2);
                        acc = fmaf(num, __builtin_amdgcn_rcpf(den), acc);
                    }
                    // epilogue for col 2u+1
                    {
                        const float vA = hAB1.x, vB = hAB1.y;
                        const float vS = hSP1.x, vP = hSP1.y;
                        const float mu11 = vA * vA, mu22 = vB * vB;
                        const float mu12 = vA * vB;
                        const float num = fmaf(2.f, mu12, SSIM_C1) *
                                          fmaf(2.f, vP - mu12, SSIM_C2);
                        const float d1  = mu11 + mu22;
                        const float den = (d1 + SSIM_C1) * ((vS - d1) + SSIM_C2);
                        acc = fmaf(num, __builtin_amdgcn_rcpf(den), acc);
                    }
                    buf ^= 1;
                }
            }
        }
    }

    // block reduction: wave shuffle, then 8 wave-sums via LDS
#pragma unroll
    for (int off = 32; off >= 1; off >>= 1)
        acc += __shfl_down(acc, off, 64);
    const int wave = x >> 6, lane = x & 63;
    if (lane == 0) red[wave] = acc;
    __syncthreads();
    if (x == 0) {
        float s = 0.f;
#pragma unroll
        for (int k = 0; k < 8; ++k) s += red[k];
        blockSums[bid] = s;
    }
}

__global__ void ssim_reduce(const float* __restrict__ bs,
                            float* __restrict__ out) {
    __shared__ double red[4];
    const int t = threadIdx.x;  // 256 threads
    double a = 0.0;
    for (int idx = t; idx < NBLOCKS; idx += 256) a += (double)bs[idx];
#pragma unroll
    for (int off = 32; off >= 1; off >>= 1)
        a += __shfl_down(a, off, 64);
    const int wave = t >> 6, lane = t & 63;
    if (lane == 0) red[wave] = a;
    __syncthreads();
    if (t == 0) {
        const double s = red[0] + red[1] + red[2] + red[3];
        out[0] = (float)(s / (double)((double)NPLANES * IMG_H * IMG_W));
    }
}

extern "C" void kernel_launch(void* const* d_in, const int* in_sizes, int n_in,
                              void* d_out, int out_size, void* d_ws, size_t ws_size,
                              hipStream_t stream) {
    const float* img1 = (const float*)d_in[0];
    const float* img2 = (const float*)d_in[1];
    float* out = (float*)d_out;
    float* bs = (float*)d_ws;   // 768 floats of scratch

    // Gaussian weights, faithful to reference: center 5.5, sigma 1.5
    W2x11 wv;
    double g[11], s = 0.0;
    for (int i = 0; i < 11; ++i) {
        const double d = (double)i - 5.5;
        g[i] = exp(-(d * d) / (2.0 * 1.5 * 1.5));
        s += g[i];
    }
    for (int i = 0; i < 11; ++i) {
        const float w = (float)(g[i] / s);
        wv.w[i] = make_float2(w, w);
    }

    ssim_main<<<NBLOCKS, 512, 0, stream>>>(img1, img2, bs, wv);
    ssim_reduce<<<1, 256, 0, stream>>>(bs, out);
}